// Round 1
// baseline (88.889 us; speedup 1.0000x reference)
//
#include <hip/hip_runtime.h>
#include <math.h>

#define BS   8
#define HW   1024
#define NP   512     // model points
#define NS   51      // hw / STEP samples
#define STEP 20
#define SW   0.01f

// One block per (b, n) sample pair. 256 threads.
__global__ __launch_bounds__(256) void add_loss_kernel(
    const float* __restrict__ pred_r,    // (BS,4,HW)
    const float* __restrict__ pred_t,    // (BS,3,HW)
    const float* __restrict__ pred_s,    // (BS,HW)
    const float* __restrict__ gt_r,      // (BS,3,3)
    const float* __restrict__ gt_t,      // (BS,3)
    const float* __restrict__ model_xyz, // (BS,3,NP)
    float* __restrict__ partials)        // (BS*NS)
{
    const int bn  = blockIdx.x;      // 0..407
    const int b   = bn / NS;
    const int n   = bn % NS;
    const int pix = n * STEP;
    const int tid = threadIdx.x;

    __shared__ float gx[NP], gy[NP], gz[NP];

    const float* Rg = gt_r + b * 9;
    const float g00 = Rg[0], g01 = Rg[1], g02 = Rg[2];
    const float g10 = Rg[3], g11 = Rg[4], g12 = Rg[5];
    const float g20 = Rg[6], g21 = Rg[7], g22 = Rg[8];
    const float tx = gt_t[b*3+0], ty = gt_t[b*3+1], tz = gt_t[b*3+2];
    const float* M = model_xyz + b * 3 * NP;

    // Stage transformed GT cloud into LDS: gt = gt_r @ M + gt_t
    for (int p = tid; p < NP; p += 256) {
        const float mx = M[p], my = M[NP + p], mz = M[2*NP + p];
        gx[p] = fmaf(g00, mx, fmaf(g01, my, fmaf(g02, mz, tx)));
        gy[p] = fmaf(g10, mx, fmaf(g11, my, fmaf(g12, mz, ty)));
        gz[p] = fmaf(g20, mx, fmaf(g21, my, fmaf(g22, mz, tz)));
    }

    // Quaternion -> rotation for this (b,n)
    float q0 = pred_r[(b*4 + 0)*HW + pix];
    float q1 = pred_r[(b*4 + 1)*HW + pix];
    float q2 = pred_r[(b*4 + 2)*HW + pix];
    float q3 = pred_r[(b*4 + 3)*HW + pix];
    const float inv = rsqrtf(q0*q0 + q1*q1 + q2*q2 + q3*q3);
    q0 *= inv; q1 *= inv; q2 *= inv; q3 *= inv;
    const float r00 = 1.f - 2.f*(q2*q2 + q3*q3);
    const float r01 = 2.f*q1*q2 - 2.f*q0*q3;
    const float r02 = 2.f*q0*q2 + 2.f*q1*q3;
    const float r10 = 2.f*q1*q2 + 2.f*q3*q0;
    const float r11 = 1.f - 2.f*(q1*q1 + q3*q3);
    const float r12 = -2.f*q0*q1 + 2.f*q2*q3;
    const float r20 = -2.f*q0*q2 + 2.f*q1*q3;
    const float r21 = 2.f*q0*q1 + 2.f*q2*q3;
    const float r22 = 1.f - 2.f*(q1*q1 + q2*q2);
    const float ptx = pred_t[(b*3 + 0)*HW + pix];
    const float pty = pred_t[(b*3 + 1)*HW + pix];
    const float ptz = pred_t[(b*3 + 2)*HW + pix];

    // Each thread owns 2 predicted points: tid and tid+256
    const int p0 = tid, p1 = tid + 256;
    float mx0 = M[p0], my0 = M[NP + p0], mz0 = M[2*NP + p0];
    float mx1 = M[p1], my1 = M[NP + p1], mz1 = M[2*NP + p1];
    const float px0 = fmaf(r00, mx0, fmaf(r01, my0, fmaf(r02, mz0, ptx)));
    const float py0 = fmaf(r10, mx0, fmaf(r11, my0, fmaf(r12, mz0, pty)));
    const float pz0 = fmaf(r20, mx0, fmaf(r21, my0, fmaf(r22, mz0, ptz)));
    const float px1 = fmaf(r00, mx1, fmaf(r01, my1, fmaf(r02, mz1, ptx)));
    const float py1 = fmaf(r10, mx1, fmaf(r11, my1, fmaf(r12, mz1, pty)));
    const float pz1 = fmaf(r20, mx1, fmaf(r21, my1, fmaf(r22, mz1, ptz)));

    __syncthreads();

    float dmin0 = 3.4e38f, dmin1 = 3.4e38f;
    #pragma unroll 4
    for (int j = 0; j < NP; ++j) {
        const float gxj = gx[j], gyj = gy[j], gzj = gz[j];
        float dx = px0 - gxj, dy = py0 - gyj, dz = pz0 - gzj;
        float d2 = fmaf(dx, dx, fmaf(dy, dy, dz*dz));
        dmin0 = fminf(dmin0, d2);
        dx = px1 - gxj; dy = py1 - gyj; dz = pz1 - gzj;
        d2 = fmaf(dx, dx, fmaf(dy, dy, dz*dz));
        dmin1 = fminf(dmin1, d2);
    }

    float sum = sqrtf(fmaxf(dmin0, 0.f)) + sqrtf(fmaxf(dmin1, 0.f));

    // Block reduction: wave shuffle (width 64), then LDS across 4 waves
    for (int off = 32; off; off >>= 1) sum += __shfl_down(sum, off, 64);
    __shared__ float wsum[4];
    if ((tid & 63) == 0) wsum[tid >> 6] = sum;
    __syncthreads();
    if (tid == 0) {
        const float s = wsum[0] + wsum[1] + wsum[2] + wsum[3];
        const float add_ij = s * (1.f / NP);
        const float ps = pred_s[b * HW + pix];
        partials[bn] = add_ij * ps - SW * logf(ps);
    }
}

__global__ __launch_bounds__(512) void finalize_kernel(
    const float* __restrict__ partials, float* __restrict__ out)
{
    const int tid = threadIdx.x;
    float v = (tid < BS * NS) ? partials[tid] : 0.f;
    for (int off = 32; off; off >>= 1) v += __shfl_down(v, off, 64);
    __shared__ float ws[8];
    if ((tid & 63) == 0) ws[tid >> 6] = v;
    __syncthreads();
    if (tid == 0) {
        float s = 0.f;
        #pragma unroll
        for (int i = 0; i < 8; ++i) s += ws[i];
        s *= 1.f / (float)(BS * NS);
        if (isinf(s) || isnan(s)) s = 0.f;
        out[0] = s;
    }
}

extern "C" void kernel_launch(void* const* d_in, const int* in_sizes, int n_in,
                              void* d_out, int out_size, void* d_ws, size_t ws_size,
                              hipStream_t stream) {
    const float* pred_r    = (const float*)d_in[0];
    const float* pred_t    = (const float*)d_in[1];
    const float* pred_s    = (const float*)d_in[2];
    // d_in[3] = mask (all ones, unused by reference math)
    const float* gt_r      = (const float*)d_in[4];
    const float* gt_t      = (const float*)d_in[5];
    const float* model_xyz = (const float*)d_in[6];
    // d_in[7] = cls_ids (unused)

    float* partials = (float*)d_ws;   // BS*NS floats
    float* out      = (float*)d_out;

    add_loss_kernel<<<BS * NS, 256, 0, stream>>>(
        pred_r, pred_t, pred_s, gt_r, gt_t, model_xyz, partials);
    finalize_kernel<<<1, 512, 0, stream>>>(partials, out);
}